// Round 9
// baseline (151.016 us; speedup 1.0000x reference)
//
#include <hip/hip_runtime.h>
#include <stdint.h>
#include <math.h>

typedef __attribute__((ext_vector_type(8))) __bf16 bf16x8;
typedef __attribute__((ext_vector_type(4))) __bf16 bf16x4;
typedef __attribute__((ext_vector_type(4))) float f32x4;

// async global->LDS 16B DMA (no VGPR round-trip). LDS dest must be
// wave-uniform base; HW writes lane i at base + i*16.
__device__ __forceinline__ void gload_lds16(const __bf16* g, __bf16* l) {
  __builtin_amdgcn_global_load_lds(
      (const __attribute__((address_space(1))) unsigned int*)g,
      (__attribute__((address_space(3))) unsigned int*)l,
      16, 0, 0);
}
__device__ __forceinline__ void gload_lds16f(const float* g, float* l) {
  __builtin_amdgcn_global_load_lds(
      (const __attribute__((address_space(1))) unsigned int*)g,
      (__attribute__((address_space(3))) unsigned int*)l,
      16, 0, 0);
}

// ---------------- outs GEMM: C[m][n] = sum_k x[m][k] * Wflat[n][k] + bias[n] ----
// M=4096, N=512, K=512. 64x64 tiles -> grid (8,64)=512 blocks (2/CU).
// REWRITE (R9): fp32 DMA double-buffer staging (gram's proven 48-us loop
// skeleton) instead of reg-staged cvt staging — the old version exposed
// full load latency every K-iter (only ~8 MFMAs of cover). fp32 tiles are
// staged raw via global_load_lds; fragment reads convert fp32->bf16 in
// registers (identical numerics to the old cvt-before-LDS path).
// 16B-slot swizzle: LDS slot s of row r holds global slot s^(r&15) -> full
// 16-way XOR spread = 2-way bank aliasing on reads (free, m136).
// Block (0,0) also zero-inits the atomic accumulators + final scalar.
__global__ __launch_bounds__(256) void k_outs(const float* __restrict__ x,
                                              const float* __restrict__ W,
                                              const float* __restrict__ bias,
                                              __bf16* __restrict__ totalbf,
                                              float* __restrict__ colsum,
                                              float* __restrict__ scal,
                                              float* __restrict__ out) {
  __shared__ float As[2][64][64];
  __shared__ float Bs[2][64][64];
  const int bj = blockIdx.x;   // 0..7  (N tiles of 64)
  const int bi = blockIdx.y;   // 0..63 (M tiles of 64)
  const int t = threadIdx.x;
  if (bj == 0 && bi == 0) {
    colsum[t] = 0.f;
    if (t < 8) scal[t] = 0.f;
    if (t == 0) out[1048576] = 0.f;
  }
  const int wid = t >> 6, lane = t & 63;
  const int wr = wid >> 1, wc = wid & 1;
  const int n16 = lane & 15, q = lane >> 4;
  const int lr = lane >> 4;             // 0..3: row within one DMA instr
  const int ls = lane & 15;             // 0..15: 16B slot within row

  f32x4 acc[2][2];
  f32x4 zero = {0.f, 0.f, 0.f, 0.f};
  for (int i = 0; i < 2; ++i)
    for (int j = 0; j < 2; ++j) acc[i][j] = zero;

  const int arow0 = bi * 64, brow0 = bj * 64;

  // stage one K-chunk (64 rows x 64 fp32) per matrix: wave wid covers rows
  // wid*16..+16 via 4 DMA instrs (4 rows each). Pre-swizzled source slot.
#define STAGE_OUTS(B, KC)                                                      \
  _Pragma("unroll") for (int p = 0; p < 4; ++p) {                              \
    int rrel = p * 4 + lr; /* row within wave's 16, also row&15 of tile */     \
    int rw = wid * 16 + rrel;                                                  \
    gload_lds16f(x + (size_t)(arow0 + rw) * 512 + (KC) + ((ls ^ rrel) << 2),   \
                 &As[B][wid * 16 + p * 4][0]);                                 \
    gload_lds16f(W + (size_t)(brow0 + rw) * 512 + (KC) + ((ls ^ rrel) << 2),   \
                 &Bs[B][wid * 16 + p * 4][0]);                                 \
  }

  STAGE_OUTS(0, 0)
  __syncthreads();   // implicit vmcnt(0): buffer 0 ready

  int buf = 0;
  for (int it = 0; it < 8; ++it) {
    if (it < 7) { STAGE_OUTS(buf ^ 1, (it + 1) * 64) }
    // compute current buffer (prefetch DMAs fly under the reads+MFMAs)
#pragma unroll
    for (int ks = 0; ks < 2; ++ks) {
      bf16x8 af[2], bfr[2];
#pragma unroll
      for (int f = 0; f < 2; ++f) {
        int rowA = wr * 32 + f * 16 + n16;     // row&15 == n16
        int rowB = wc * 32 + f * 16 + n16;
        int s0 = ks * 8 + q * 2;               // even 16B-slot
        f32x4 alo = *(const f32x4*)&As[buf][rowA][(s0 ^ n16) << 2];
        f32x4 ahi = *(const f32x4*)&As[buf][rowA][((s0 + 1) ^ n16) << 2];
        f32x4 blo = *(const f32x4*)&Bs[buf][rowB][(s0 ^ n16) << 2];
        f32x4 bhi = *(const f32x4*)&Bs[buf][rowB][((s0 + 1) ^ n16) << 2];
        af[f]  = (bf16x8){(__bf16)alo[0], (__bf16)alo[1], (__bf16)alo[2], (__bf16)alo[3],
                          (__bf16)ahi[0], (__bf16)ahi[1], (__bf16)ahi[2], (__bf16)ahi[3]};
        bfr[f] = (bf16x8){(__bf16)blo[0], (__bf16)blo[1], (__bf16)blo[2], (__bf16)blo[3],
                          (__bf16)bhi[0], (__bf16)bhi[1], (__bf16)bhi[2], (__bf16)bhi[3]};
      }
      for (int fr = 0; fr < 2; ++fr)
        for (int fc = 0; fc < 2; ++fc)
          acc[fr][fc] = __builtin_amdgcn_mfma_f32_16x16x32_bf16(af[fr], bfr[fc], acc[fr][fc], 0, 0, 0);
    }
    __syncthreads();   // drains prefetch DMA + protects buffer reuse
    buf ^= 1;
  }
#undef STAGE_OUTS

  for (int fc = 0; fc < 2; ++fc) {
    int n_g = bj * 64 + wc * 32 + fc * 16 + n16;   // 0..511
    float bv = bias[n_g];
    int l = n_g >> 8, o = n_g & 255;
    for (int fr = 0; fr < 2; ++fr) {
      for (int r = 0; r < 4; ++r) {
        int m_g = bi * 64 + wr * 32 + fr * 16 + q * 4 + r;
        float v = acc[fr][fc][r] + bv;
        totalbf[(size_t)(l * 4096 + m_g) * 256 + o] = (__bf16)v;
      }
    }
  }
}

// ------- fused: gates + sq + colsum + combine + bandwidth finalize ------------
// 256 blocks x 256 thr (R9: was 128 — half the CUs sat idle); wave w owns rows
// blk*16 + w*4 .. +4, computes their gates in-register (butterfly shfl_xor).
__global__ __launch_bounds__(256) void k_sqc(const __bf16* __restrict__ tot,
                                             const float* __restrict__ x,
                                             const float* __restrict__ Waux,
                                             const float* __restrict__ baux,
                                             float* __restrict__ sq,
                                             float* __restrict__ colsum,
                                             float* __restrict__ scal,
                                             float* __restrict__ out) {
  __shared__ float lcol[4][256];
  __shared__ float wsq[4];
  __shared__ unsigned int isLast;
  const int t = threadIdx.x;
  const int wave = t >> 6, lane = t & 63;

  // ---- gates phase: rows m = blk*16 + wave*4 + it ----
  const float4* wa = (const float4*)(Waux);          // row 0: 128 float4
  const float4* wb = (const float4*)(Waux + 512);    // row 1
  float4 a0 = wa[lane * 2], a1 = wa[lane * 2 + 1];
  float4 b0 = wb[lane * 2], b1 = wb[lane * 2 + 1];
  const float bx0 = baux[0], bx1 = baux[1];
  float g0[4], g1[4];
#pragma unroll
  for (int it = 0; it < 4; ++it) {
    int m = blockIdx.x * 16 + wave * 4 + it;
    const float4* xr = (const float4*)(x + (size_t)m * 512);
    float4 x0 = xr[lane * 2], x1 = xr[lane * 2 + 1];
    float p0 = x0.x * a0.x + x0.y * a0.y + x0.z * a0.z + x0.w * a0.w
             + x1.x * a1.x + x1.y * a1.y + x1.z * a1.z + x1.w * a1.w;
    float p1 = x0.x * b0.x + x0.y * b0.y + x0.z * b0.z + x0.w * b0.w
             + x1.x * b1.x + x1.y * b1.y + x1.z * b1.z + x1.w * b1.w;
    for (int off = 32; off; off >>= 1) {
      p0 += __shfl_xor(p0, off, 64);
      p1 += __shfl_xor(p1, off, 64);
    }
    p0 += bx0; p1 += bx1;
    float mm = fmaxf(p0, p1);
    float e0 = __expf(p0 - mm), e1 = __expf(p1 - mm);
    float inv = 1.f / (e0 + e1);
    g0[it] = e0 * inv;
    g1[it] = e1 * inv;
  }

  // ---- sq + colsum + combine ----
  float c0 = 0.f, c1 = 0.f, c2 = 0.f, c3 = 0.f;
  float bsq = 0.f;
#pragma unroll
  for (int it = 0; it < 4; ++it) {
    int m = blockIdx.x * 16 + wave * 4 + it;      // 0..4095
    bf16x4 v0 = *(const bf16x4*)(tot + (size_t)m * 256 + lane * 4);
    bf16x4 v1 = *(const bf16x4*)(tot + (size_t)(4096 + m) * 256 + lane * 4);
    float f00 = v0[0], f01 = v0[1], f02 = v0[2], f03 = v0[3];
    float f10 = v1[0], f11 = v1[1], f12 = v1[2], f13 = v1[3];
    float s0 = f00 * f00 + f01 * f01 + f02 * f02 + f03 * f03;
    float s1 = f10 * f10 + f11 * f11 + f12 * f12 + f13 * f13;
    for (int off = 32; off; off >>= 1) {
      s0 += __shfl_down(s0, off, 64);
      s1 += __shfl_down(s1, off, 64);
    }
    if (lane == 0) { sq[m] = s0; sq[4096 + m] = s1; bsq += s0 + s1; }
    c0 += f00 + f10; c1 += f01 + f11; c2 += f02 + f12; c3 += f03 + f13;
    float4 r;
    r.x = g0[it] * f00 + g1[it] * f10;
    r.y = g0[it] * f01 + g1[it] * f11;
    r.z = g0[it] * f02 + g1[it] * f12;
    r.w = g0[it] * f03 + g1[it] * f13;
    *(float4*)(out + (size_t)m * 256 + lane * 4) = r;
  }
  lcol[wave][lane * 4 + 0] = c0;
  lcol[wave][lane * 4 + 1] = c1;
  lcol[wave][lane * 4 + 2] = c2;
  lcol[wave][lane * 4 + 3] = c3;
  if (lane == 0) wsq[wave] = bsq;
  __syncthreads();
  float s2 = lcol[0][t] + lcol[1][t] + lcol[2][t] + lcol[3][t];
  atomicAdd(&colsum[t], s2);
  if (t == 0) atomicAdd(&scal[4], wsq[0] + wsq[1] + wsq[2] + wsq[3]);
  __threadfence();
  if (t == 0) {
    unsigned int c = atomicAdd((unsigned int*)(scal + 5), 1u);
    isLast = (c == 255u) ? 1u : 0u;
  }
  __syncthreads();
  if (isLast) {
    __threadfence();
    float cv = atomicAdd(&colsum[t], 0.0f);      // coherent read
    lcol[0][t] = cv * cv;
    __syncthreads();
    for (int off = 128; off; off >>= 1) {
      if (t < off) lcol[0][t] += lcol[0][t + off];
      __syncthreads();
    }
    if (t == 0) {
      float sumsq = atomicAdd(&scal[4], 0.0f);
      double sumdist = 2.0 * 8192.0 * (double)sumsq - 2.0 * (double)lcol[0][0];
      double bw = sumdist / (8192.0 * 8192.0 - 8192.0) / 4.0;  // / KERNEL_MUL^(5//2)
      scal[1] = (float)(1.4426950408889634 / (bw * 16.0));     // g4 * log2(e)
      scal[2] = (float)bw;
    }
  }
}

// ---------------- Gram tiles + fused multi-bandwidth kernel sum ---------------
// R7/R8-proven structure (47.9-48.7 us): double-buffered LDS, prefetch DMAs
// issued before compute, plain __syncthreads, fire-and-forget atomic with the
// final -S/2^24 scale folded in. UNCHANGED.
__global__ __launch_bounds__(256) void k_gram(const __bf16* __restrict__ tot,
                                              const float* __restrict__ sq,
                                              const float* __restrict__ scal,
                                              float* __restrict__ out) {
  const int b = blockIdx.x;                    // 0..2079
  const int nid = (b & 7) * 260 + (b >> 3);    // XCD-chunked, bijective (2080=8*260)
  int ti = (int)((129.0 - sqrt(129.0 * 129.0 - 8.0 * (double)nid)) * 0.5);
  while (64 * ti - ti * (ti - 1) / 2 > nid) --ti;
  while (64 * (ti + 1) - (ti + 1) * ti / 2 <= nid) ++ti;
  const int tj = ti + (nid - (64 * ti - ti * (ti - 1) / 2));

  __shared__ __bf16 As[2][128][64];
  __shared__ __bf16 Bs[2][128][64];
  __shared__ float sqi[128], sqj[128];
  __shared__ float wred[4];
  const int t = threadIdx.x;
  const int wid = t >> 6, lane = t & 63;
  const int wr = wid >> 1, wc = wid & 1;
  const int n16 = lane & 15, q = lane >> 4;
  const int sx = (n16 & 7) << 3;     // read-side swizzle (element units)
  const int lr = lane >> 3;          // 0..7: row within 8-row DMA chunk
  const int ls = lane & 7;           // 0..7: 16B slot within row

  const float g = scal[1];           // log2e / (bw*16)
  if (t < 128) sqi[t] = sq[ti * 128 + t] * g;          // pre-scaled by g
  else         sqj[t - 128] = sq[tj * 128 + (t - 128)] * g;

  f32x4 acc[4][4];
  f32x4 zero = {0.f, 0.f, 0.f, 0.f};
  for (int i = 0; i < 4; ++i)
    for (int j = 0; j < 4; ++j) acc[i][j] = zero;

  // pre-swizzled per-lane global source: LDS slot ls of row r holds global
  // slot ls^(r&7); r&7 == lr for every chunk (rows step by 8).
  const __bf16* gA = tot + (size_t)(ti * 128 + wid * 32 + lr) * 256 + ((ls ^ lr) << 3);
  const __bf16* gB = tot + (size_t)(tj * 128 + wid * 32 + lr) * 256 + ((ls ^ lr) << 3);

  // prologue: stage chunk 0 into buffer 0 (wave wid covers rows wid*32..+32)
#pragma unroll
  for (int p = 0; p < 4; ++p) {
    gload_lds16(gA + p * 8 * 256, &As[0][wid * 32 + p * 8][0]);
    gload_lds16(gB + p * 8 * 256, &Bs[0][wid * 32 + p * 8][0]);
  }
  __syncthreads();   // implicit vmcnt(0): buffer 0 ready

  int buf = 0;
  for (int it = 0; it < 4; ++it) {
    // issue async DMA for next K-chunk into the other buffer
    if (it < 3) {
      const int kc = (it + 1) * 64;
#pragma unroll
      for (int p = 0; p < 4; ++p) {
        gload_lds16(gA + p * 8 * 256 + kc, &As[buf ^ 1][wid * 32 + p * 8][0]);
        gload_lds16(gB + p * 8 * 256 + kc, &Bs[buf ^ 1][wid * 32 + p * 8][0]);
      }
    }
    // compute current buffer (loads fly under the MFMAs)
#pragma unroll
    for (int ks = 0; ks < 2; ++ks) {
      bf16x8 af[4], bfr[4];
#pragma unroll
      for (int f = 0; f < 4; ++f) {
        af[f]  = *(const bf16x8*)&As[buf][wr * 64 + f * 16 + n16][(ks * 32 + q * 8) ^ sx];
        bfr[f] = *(const bf16x8*)&Bs[buf][wc * 64 + f * 16 + n16][(ks * 32 + q * 8) ^ sx];
      }
      for (int fr = 0; fr < 4; ++fr)
        for (int fc = 0; fc < 4; ++fc)
          acc[fr][fc] = __builtin_amdgcn_mfma_f32_16x16x32_bf16(af[fr], bfr[fc], acc[fr][fc], 0, 0, 0);
    }
    __syncthreads();   // drains prefetch DMA (vmcnt 0) + protects buffer reuse
    buf ^= 1;
  }

  // epilogue: arg = 2g*acc - (g*si + g*sj); ksum = u+u2+u4+u8+u16, u=exp2(arg)
  const float twog = 2.f * g;
  float lsum = 0.f;
  for (int fr = 0; fr < 4; ++fr) {
    for (int r = 0; r < 4; ++r) {
      float gsi = sqi[wr * 64 + fr * 16 + q * 4 + r];
      for (int fc = 0; fc < 4; ++fc) {
        float gsj = sqj[wc * 64 + fc * 16 + n16];
        float u = exp2f(fmaf(twog, acc[fr][fc][r], -(gsi + gsj)));
        float u2 = u * u, u4 = u2 * u2, u8 = u4 * u4;
        float s1 = fmaf(u8, u8, u8);           // u16 + u8
        lsum += (u + u2) + (u4 + s1);
      }
    }
  }
  for (int off = 32; off; off >>= 1) lsum += __shfl_down(lsum, off, 64);
  if (lane == 0) wred[wid] = lsum;
  __syncthreads();
  if (t == 0) {
    float blocksum = wred[0] + wred[1] + wred[2] + wred[3];
    float sgn = ((ti < 32) == (tj < 32)) ? 1.f : -1.f;
    float wgt = (ti == tj) ? sgn : 2.f * sgn;
    // final scale folded in: out[1048576] = -S/2^24, accumulated directly
    atomicAdd(out + 1048576, wgt * blocksum * (-1.f / 16777216.f));
  }
}

extern "C" void kernel_launch(void* const* d_in, const int* in_sizes, int n_in,
                              void* d_out, int out_size, void* d_ws, size_t ws_size,
                              hipStream_t stream) {
  const float* x    = (const float*)d_in[0];
  const float* Waux = (const float*)d_in[1];
  const float* baux = (const float*)d_in[2];
  const float* W    = (const float*)d_in[3];
  const float* bias = (const float*)d_in[4];
  float* out = (float*)d_out;

  char* ws = (char*)d_ws;
  __bf16* totalbf = (__bf16*)ws;                    // 8192*256*2 = 4,194,304 B
  float* sq      = (float*)(ws + 4194304);          // 8192 f32
  float* colsum  = (float*)(ws + 4227072);          // 256 f32
  float* scal    = (float*)(ws + 4228096);          // [1]=g4l2 [2]=bw [4]=sumsq [5]=sqc-cnt

  k_outs<<<dim3(8, 64), 256, 0, stream>>>(x, W, bias, totalbf, colsum, scal, out);
  k_sqc<<<256, 256, 0, stream>>>(totalbf, x, Waux, baux, sq, colsum, scal, out);
  k_gram<<<2080, 256, 0, stream>>>(totalbf, sq, scal, out);
}

// Round 11
// 140.665 us; speedup vs baseline: 1.0736x; 1.0736x over previous
//
#include <hip/hip_runtime.h>
#include <stdint.h>
#include <math.h>

typedef __attribute__((ext_vector_type(8))) __bf16 bf16x8;
typedef __attribute__((ext_vector_type(4))) __bf16 bf16x4;
typedef __attribute__((ext_vector_type(4))) float f32x4;

// -------- fragment-major tiled layout for totalbf --------
// 16-row x 32-col fragment blocks in MFMA order. Element (row, o):
//   row-block = row>>4 (4096 elems each), col-block = o>>5 (512 elems each),
//   inner = q<<7 | n16<<3 | e  with q=(o>>3)&3, n16=row&15, e=o&7  (0..511).
// Lane l = q*16+n16 of a wave then owns the 8 consecutive elems at +l*8:
// one 16x32 fragment = ONE coalesced 1KB wave-load (dwordx4/lane).
// (R10 bug: inner used q<<8|n16<<4 -> spanned 1024 in a 512 slot = collisions.)
__device__ __forceinline__ size_t tbidx(int row, int o) {
  return ((size_t)(row >> 4) << 12) + ((o >> 5) << 9) +
         (((o >> 3) & 3) << 7) + ((row & 15) << 3) + (o & 7);
}

// ---------------- outs GEMM: C[m][n] = sum_k x[m][k] * Wflat[n][k] + bias[n] ----
// M=4096, N=512, K=512. 64x64 tiles -> grid (8,64)=512 blocks.
// R8-proven body (reg-staged bf16, 16KB LDS, swizzled); only the epilogue
// store address uses the fragment-major layout.
// Block (0,0) also zero-inits the atomic accumulators + final scalar.
__global__ __launch_bounds__(256) void k_outs(const float* __restrict__ x,
                                              const float* __restrict__ W,
                                              const float* __restrict__ bias,
                                              __bf16* __restrict__ totalbf,
                                              float* __restrict__ colsum,
                                              float* __restrict__ scal,
                                              float* __restrict__ out) {
  __shared__ __bf16 As[64][64];
  __shared__ __bf16 Bs[64][64];
  const int bj = blockIdx.x;   // 0..7  (N tiles of 64)
  const int bi = blockIdx.y;   // 0..63 (M tiles of 64)
  const int t = threadIdx.x;
  if (bj == 0 && bi == 0) {
    colsum[t] = 0.f;
    if (t < 8) scal[t] = 0.f;
    if (t == 0) out[1048576] = 0.f;
  }
  const int wid = t >> 6, lane = t & 63;
  const int wr = wid >> 1, wc = wid & 1;
  const int n16 = lane & 15, q = lane >> 4;
  const int sx = (n16 & 7) << 3;        // read-side swizzle (element units)
  const int erow = t >> 4;              // 0..15 (+p*16)
  const int c4 = (t & 15) << 2;         // 0..60

  f32x4 acc[2][2];
  f32x4 zero = {0.f, 0.f, 0.f, 0.f};
  for (int i = 0; i < 2; ++i)
    for (int j = 0; j < 2; ++j) acc[i][j] = zero;

  const int arow0 = bi * 64, brow0 = bj * 64;

  float4 ra[4], rb[4];
#pragma unroll
  for (int p = 0; p < 4; ++p) {
    int row = p * 16 + erow;
    ra[p] = *(const float4*)(x + (size_t)(arow0 + row) * 512 + c4);
    rb[p] = *(const float4*)(W + (size_t)(brow0 + row) * 512 + c4);
  }

  for (int kc = 0; kc < 512; kc += 64) {
#pragma unroll
    for (int p = 0; p < 4; ++p) {
      int row = p * 16 + erow;
      int col = c4 ^ ((row & 7) << 3);
      float4 va = ra[p];
      bf16x4 ba = {(__bf16)va.x, (__bf16)va.y, (__bf16)va.z, (__bf16)va.w};
      *(bf16x4*)&As[row][col] = ba;
      float4 vb = rb[p];
      bf16x4 bb = {(__bf16)vb.x, (__bf16)vb.y, (__bf16)vb.z, (__bf16)vb.w};
      *(bf16x4*)&Bs[row][col] = bb;
    }
    __syncthreads();
    // issue next-tile global loads AFTER the barrier: they fly under the MFMAs
    if (kc < 448) {
#pragma unroll
      for (int p = 0; p < 4; ++p) {
        int row = p * 16 + erow;
        ra[p] = *(const float4*)(x + (size_t)(arow0 + row) * 512 + kc + 64 + c4);
        rb[p] = *(const float4*)(W + (size_t)(brow0 + row) * 512 + kc + 64 + c4);
      }
    }
#pragma unroll
    for (int ks = 0; ks < 2; ++ks) {
      bf16x8 af[2], bfr[2];
#pragma unroll
      for (int f = 0; f < 2; ++f) {
        af[f]  = *(const bf16x8*)&As[wr * 32 + f * 16 + n16][(ks * 32 + q * 8) ^ sx];
        bfr[f] = *(const bf16x8*)&Bs[wc * 32 + f * 16 + n16][(ks * 32 + q * 8) ^ sx];
      }
      for (int fr = 0; fr < 2; ++fr)
        for (int fc = 0; fc < 2; ++fc)
          acc[fr][fc] = __builtin_amdgcn_mfma_f32_16x16x32_bf16(af[fr], bfr[fc], acc[fr][fc], 0, 0, 0);
    }
    __syncthreads();
  }

  for (int fc = 0; fc < 2; ++fc) {
    int n_g = bj * 64 + wc * 32 + fc * 16 + n16;   // 0..511
    float bv = bias[n_g];
    int l = n_g >> 8, o = n_g & 255;
    for (int fr = 0; fr < 2; ++fr) {
      for (int r = 0; r < 4; ++r) {
        int m_g = bi * 64 + wr * 32 + fr * 16 + q * 4 + r;
        float v = acc[fr][fc][r] + bv;
        totalbf[tbidx(l * 4096 + m_g, o)] = (__bf16)v;
      }
    }
  }
}

// ------- fused: gates + sq + colsum + combine + bandwidth finalize ------------
// R8-proven structure (128 blocks, wave owns 8 row-pairs); totalbf reads use
// the fragment-major layout (bf16x4 at o=lane*4 stays within one e-group).
__global__ __launch_bounds__(256) void k_sqc(const __bf16* __restrict__ tot,
                                             const float* __restrict__ x,
                                             const float* __restrict__ Waux,
                                             const float* __restrict__ baux,
                                             float* __restrict__ sq,
                                             float* __restrict__ colsum,
                                             float* __restrict__ scal,
                                             float* __restrict__ out) {
  __shared__ float lcol[4][256];
  __shared__ float wsq[4];
  __shared__ unsigned int isLast;
  const int t = threadIdx.x;
  const int wave = t >> 6, lane = t & 63;

  // ---- gates phase: rows m = blk*32 + wave*8 + it ----
  const float4* wa = (const float4*)(Waux);          // row 0: 128 float4
  const float4* wb = (const float4*)(Waux + 512);    // row 1
  float4 a0 = wa[lane * 2], a1 = wa[lane * 2 + 1];
  float4 b0 = wb[lane * 2], b1 = wb[lane * 2 + 1];
  const float bx0 = baux[0], bx1 = baux[1];
  float g0[8], g1[8];
#pragma unroll
  for (int it = 0; it < 8; ++it) {
    int m = blockIdx.x * 32 + wave * 8 + it;
    const float4* xr = (const float4*)(x + (size_t)m * 512);
    float4 x0 = xr[lane * 2], x1 = xr[lane * 2 + 1];
    float p0 = x0.x * a0.x + x0.y * a0.y + x0.z * a0.z + x0.w * a0.w
             + x1.x * a1.x + x1.y * a1.y + x1.z * a1.z + x1.w * a1.w;
    float p1 = x0.x * b0.x + x0.y * b0.y + x0.z * b0.z + x0.w * b0.w
             + x1.x * b1.x + x1.y * b1.y + x1.z * b1.z + x1.w * b1.w;
    for (int off = 32; off; off >>= 1) {
      p0 += __shfl_xor(p0, off, 64);
      p1 += __shfl_xor(p1, off, 64);
    }
    p0 += bx0; p1 += bx1;
    float mm = fmaxf(p0, p1);
    float e0 = __expf(p0 - mm), e1 = __expf(p1 - mm);
    float inv = 1.f / (e0 + e1);
    g0[it] = e0 * inv;
    g1[it] = e1 * inv;
  }

  // ---- sq + colsum + combine ----
  float c0 = 0.f, c1 = 0.f, c2 = 0.f, c3 = 0.f;
  float bsq = 0.f;
#pragma unroll
  for (int it = 0; it < 8; ++it) {
    int m = blockIdx.x * 32 + wave * 8 + it;      // 0..4095
    bf16x4 v0 = *(const bf16x4*)(tot + tbidx(m, lane * 4));
    bf16x4 v1 = *(const bf16x4*)(tot + tbidx(4096 + m, lane * 4));
    float f00 = v0[0], f01 = v0[1], f02 = v0[2], f03 = v0[3];
    float f10 = v1[0], f11 = v1[1], f12 = v1[2], f13 = v1[3];
    float s0 = f00 * f00 + f01 * f01 + f02 * f02 + f03 * f03;
    float s1 = f10 * f10 + f11 * f11 + f12 * f12 + f13 * f13;
    for (int off = 32; off; off >>= 1) {
      s0 += __shfl_down(s0, off, 64);
      s1 += __shfl_down(s1, off, 64);
    }
    if (lane == 0) { sq[m] = s0; sq[4096 + m] = s1; bsq += s0 + s1; }
    c0 += f00 + f10; c1 += f01 + f11; c2 += f02 + f12; c3 += f03 + f13;
    float4 r;
    r.x = g0[it] * f00 + g1[it] * f10;
    r.y = g0[it] * f01 + g1[it] * f11;
    r.z = g0[it] * f02 + g1[it] * f12;
    r.w = g0[it] * f03 + g1[it] * f13;
    *(float4*)(out + (size_t)m * 256 + lane * 4) = r;
  }
  lcol[wave][lane * 4 + 0] = c0;
  lcol[wave][lane * 4 + 1] = c1;
  lcol[wave][lane * 4 + 2] = c2;
  lcol[wave][lane * 4 + 3] = c3;
  if (lane == 0) wsq[wave] = bsq;
  __syncthreads();
  float s2 = lcol[0][t] + lcol[1][t] + lcol[2][t] + lcol[3][t];
  atomicAdd(&colsum[t], s2);
  if (t == 0) atomicAdd(&scal[4], wsq[0] + wsq[1] + wsq[2] + wsq[3]);
  __threadfence();
  if (t == 0) {
    unsigned int c = atomicAdd((unsigned int*)(scal + 5), 1u);
    isLast = (c == 127u) ? 1u : 0u;
  }
  __syncthreads();
  if (isLast) {
    __threadfence();
    float cv = atomicAdd(&colsum[t], 0.0f);      // coherent read
    lcol[0][t] = cv * cv;
    __syncthreads();
    for (int off = 128; off; off >>= 1) {
      if (t < off) lcol[0][t] += lcol[0][t + off];
      __syncthreads();
    }
    if (t == 0) {
      float sumsq = atomicAdd(&scal[4], 0.0f);
      double sumdist = 2.0 * 8192.0 * (double)sumsq - 2.0 * (double)lcol[0][0];
      double bw = sumdist / (8192.0 * 8192.0 - 8192.0) / 4.0;  // / KERNEL_MUL^(5//2)
      scal[1] = (float)(1.4426950408889634 / (bw * 16.0));     // g4 * log2(e)
      scal[2] = (float)bw;
    }
  }
}

// ---------------- Gram tiles + fused multi-bandwidth kernel sum ---------------
// DIRECT-FRAGMENT v2 (fixed): with fragment-major totalbf, each 16x32 A/B
// fragment is ONE coalesced 1KB wave-load (lane l at +l*8 elems = 16B) — no
// 16-line gather (R5's failure), no LDS tiles, no barriers, no staging.
// Per wave: 64 coalesced loads || 128 MFMAs, compiler free-pipelines; LDS ~1KB
// so occupancy is VGPR-bound. Triangular XCD-chunked grid, fire-and-forget
// atomic with final scale folded in (proven R7/R8).
__global__ __launch_bounds__(256) void k_gram(const __bf16* __restrict__ tot,
                                              const float* __restrict__ sq,
                                              const float* __restrict__ scal,
                                              float* __restrict__ out) {
  const int b = blockIdx.x;                    // 0..2079
  const int nid = (b & 7) * 260 + (b >> 3);    // XCD-chunked, bijective (2080=8*260)
  int ti = (int)((129.0 - sqrt(129.0 * 129.0 - 8.0 * (double)nid)) * 0.5);
  while (64 * ti - ti * (ti - 1) / 2 > nid) --ti;
  while (64 * (ti + 1) - (ti + 1) * ti / 2 <= nid) ++ti;
  const int tj = ti + (nid - (64 * ti - ti * (ti - 1) / 2));

  __shared__ float sqi[128], sqj[128];
  __shared__ float wred[4];
  const int t = threadIdx.x;
  const int wid = t >> 6, lane = t & 63;
  const int wr = wid >> 1, wc = wid & 1;
  const int n16 = lane & 15, q = lane >> 4;

  const float g = scal[1];           // log2e / (bw*16)
  if (t < 128) sqi[t] = sq[ti * 128 + t] * g;          // pre-scaled by g
  else         sqj[t - 128] = sq[tj * 128 + (t - 128)] * g;

  f32x4 acc[4][4];
  f32x4 zero = {0.f, 0.f, 0.f, 0.f};
  for (int i = 0; i < 4; ++i)
    for (int j = 0; j < 4; ++j) acc[i][j] = zero;

  // fragment bases: A-frag f covers rows ti*128+wr*64+f*16..+16 — row-block
  // (ti*8+wr*4+f); lane l's 16B slice at +l*8 elems; col-block ks at +ks*512.
  const __bf16* pA = tot + ((size_t)(ti * 8 + wr * 4) << 12) + lane * 8;
  const __bf16* pB = tot + ((size_t)(tj * 8 + wc * 4) << 12) + lane * 8;

#pragma unroll
  for (int ks = 0; ks < 8; ++ks) {
    bf16x8 af[4], bfr[4];
#pragma unroll
    for (int f = 0; f < 4; ++f) {
      af[f]  = *(const bf16x8*)(pA + ((size_t)f << 12) + ((size_t)ks << 9));
      bfr[f] = *(const bf16x8*)(pB + ((size_t)f << 12) + ((size_t)ks << 9));
    }
    for (int fr = 0; fr < 4; ++fr)
      for (int fc = 0; fc < 4; ++fc)
        acc[fr][fc] = __builtin_amdgcn_mfma_f32_16x16x32_bf16(af[fr], bfr[fc], acc[fr][fc], 0, 0, 0);
  }

  __syncthreads();   // publish sqi/sqj (cross-wave)

  // epilogue: arg = 2g*acc - (g*si + g*sj); ksum = u+u2+u4+u8+u16, u=exp2(arg)
  const float twog = 2.f * g;
  float lsum = 0.f;
  for (int fr = 0; fr < 4; ++fr) {
    for (int r = 0; r < 4; ++r) {
      float gsi = sqi[wr * 64 + fr * 16 + q * 4 + r];
      for (int fc = 0; fc < 4; ++fc) {
        float gsj = sqj[wc * 64 + fc * 16 + n16];
        float u = exp2f(fmaf(twog, acc[fr][fc][r], -(gsi + gsj)));
        float u2 = u * u, u4 = u2 * u2, u8 = u4 * u4;
        float s1 = fmaf(u8, u8, u8);           // u16 + u8
        lsum += (u + u2) + (u4 + s1);
      }
    }
  }
  for (int off = 32; off; off >>= 1) lsum += __shfl_down(lsum, off, 64);
  if (lane == 0) wred[wid] = lsum;
  __syncthreads();
  if (t == 0) {
    float blocksum = wred[0] + wred[1] + wred[2] + wred[3];
    float sgn = ((ti < 32) == (tj < 32)) ? 1.f : -1.f;
    float wgt = (ti == tj) ? sgn : 2.f * sgn;
    // final scale folded in: out[1048576] = -S/2^24, accumulated directly
    atomicAdd(out + 1048576, wgt * blocksum * (-1.f / 16777216.f));
  }
}

extern "C" void kernel_launch(void* const* d_in, const int* in_sizes, int n_in,
                              void* d_out, int out_size, void* d_ws, size_t ws_size,
                              hipStream_t stream) {
  const float* x    = (const float*)d_in[0];
  const float* Waux = (const float*)d_in[1];
  const float* baux = (const float*)d_in[2];
  const float* W    = (const float*)d_in[3];
  const float* bias = (const float*)d_in[4];
  float* out = (float*)d_out;

  char* ws = (char*)d_ws;
  __bf16* totalbf = (__bf16*)ws;                    // 8192*256*2 = 4,194,304 B (tiled)
  float* sq      = (float*)(ws + 4194304);          // 8192 f32
  float* colsum  = (float*)(ws + 4227072);          // 256 f32
  float* scal    = (float*)(ws + 4228096);          // [1]=g4l2 [2]=bw [4]=sumsq [5]=sqc-cnt

  k_outs<<<dim3(8, 64), 256, 0, stream>>>(x, W, bias, totalbf, colsum, scal, out);
  k_sqc<<<128, 256, 0, stream>>>(totalbf, x, Waux, baux, sq, colsum, scal, out);
  k_gram<<<2080, 256, 0, stream>>>(totalbf, sq, scal, out);
}